// Round 13
// baseline (179.401 us; speedup 1.0000x reference)
//
#include <hip/hip_runtime.h>

// TCN, last-timestep receptive-field cone. 5 dispatches, split-K partials,
// consumer-side fused reduce at staging. Amplification-minimized geometry:
//   kA: L0 conv x->P0[4][512][11][64] (ks=4); down x->PD[4][512][5][64] (ks=4)
//   kB: L1 conv (stage B1=relu(sum4 P0+b1_0)) -> P1[8][512][5][64]
//       + tail: PDs[512][5][64] = sum4 PD (pre-reduce for kC)
//   kC: L2 conv OCT=64 (stage H0=relu(relu(sum8 P1+b2_0)+PDs+bd0))
//       -> P2[8][512][3][64]; ocp==0 also stores H0f[512][64] (u=4, t=1023)
//   kD: L3 conv OCT=64 (stage B2=relu(sum8 P2+b1_1)) -> P3[8][512][64]
//   kE: fc with H1=relu(relu(sum8 P3+b2_1)+H0f) inline
// t-maps (verified rounds 4/10/11/12): L0 u=t+kk (x t=1011+u); down u=t
// (x t=1015+2u); L1 u=2t+kk; L2 u=t+kk; L3 u=kk; residual = H0 u=4.

__device__ __forceinline__ float relu(float v) { return fmaxf(v, 0.f); }
__device__ __forceinline__ float4 relu4(float4 v) {
  v.x = fmaxf(v.x, 0.f); v.y = fmaxf(v.y, 0.f);
  v.z = fmaxf(v.z, 0.f); v.w = fmaxf(v.w, 0.f);
  return v;
}
__device__ __forceinline__ float4 add4(float4 a, float4 b) {
  a.x += b.x; a.y += b.y; a.z += b.z; a.w += b.w;
  return a;
}
__device__ __forceinline__ float4 addc4(float4 a, float c) {
  a.x += c; a.y += c; a.z += c; a.w += c;
  return a;
}
#define F4(q) (*(const float4*)(q))

// ===== kA: blocks 0..127 L0 (32 ocp x 4 ks); 128..191 down (16 x 4) =======
__global__ __launch_bounds__(256) void kA(const float* __restrict__ x,
                                          const float* __restrict__ w1_0,
                                          const float* __restrict__ wd0,
                                          float* __restrict__ P0,
                                          float* __restrict__ PD) {
  __shared__ float smem[14288];  // L0: 768 W + 13520 X(padded)
  const int tid = threadIdx.x, lane = tid & 63, wv = tid >> 6;
  if (blockIdx.x < 128) {
    const int ocp = blockIdx.x >> 2, ks = blockIdx.x & 3, oc0 = ocp * 16;
    float* Als = smem;        // [16c][3kk][16oc]
    float* Bls = smem + 768;  // [(c*13+u)*65+b]
    float acc[4][11];
#pragma unroll
    for (int i = 0; i < 4; ++i)
#pragma unroll
      for (int t = 0; t < 11; ++t) acc[i][t] = 0.f;
    for (int ch = 0; ch < 4; ++ch) {
      const int c0 = ks * 64 + ch * 16;
      if (ch) __syncthreads();
      for (int idx = tid; idx < 768; idx += 256) {
        int i = idx / 48, r = idx % 48, c = r / 3, kk = r % 3;
        Als[(c * 3 + kk) * 16 + i] = w1_0[(oc0 + i) * 768 + (c0 + c) * 3 + kk];
      }
      for (int idx = tid; idx < 13312; idx += 256) {
        int c = idx & 15, b = (idx >> 4) & 63, u = idx >> 10;
        Bls[(c * 13 + u) * 65 + b] = x[(b * 1024 + 1011 + u) * 256 + c0 + c];
      }
      __syncthreads();
      for (int c = 0; c < 16; ++c) {
        float bv[13];
#pragma unroll
        for (int u = 0; u < 13; ++u) bv[u] = Bls[(c * 13 + u) * 65 + lane];
        float av[3][4];
#pragma unroll
        for (int kk = 0; kk < 3; ++kk)
          *(float4*)av[kk] = F4(&Als[(c * 3 + kk) * 16 + wv * 4]);
#pragma unroll
        for (int i = 0; i < 4; ++i)
#pragma unroll
          for (int t = 0; t < 11; ++t)
#pragma unroll
            for (int kk = 0; kk < 3; ++kk)
              acc[i][t] += av[kk][i] * bv[t + kk];
      }
    }
#pragma unroll
    for (int i = 0; i < 4; ++i)
#pragma unroll
      for (int t = 0; t < 11; ++t)
        P0[((ks * 512 + oc0 + wv * 4 + i) * 11 + t) * 64 + lane] = acc[i][t];
  } else {
    const int q = blockIdx.x - 128;
    const int ocp = q >> 2, ks = q & 3, oc0 = ocp * 32;
    float* Ad = smem;        // [16c][32oc]
    float* Bd = smem + 512;  // [(c*5+u)*65+b]
    float acc[8][5];
#pragma unroll
    for (int i = 0; i < 8; ++i)
#pragma unroll
      for (int t = 0; t < 5; ++t) acc[i][t] = 0.f;
    for (int ch = 0; ch < 4; ++ch) {
      const int c0 = ks * 64 + ch * 16;
      if (ch) __syncthreads();
      for (int idx = tid; idx < 512; idx += 256) {
        int i = idx & 31, c = idx >> 5;
        Ad[c * 32 + i] = wd0[(oc0 + i) * 256 + c0 + c];
      }
      for (int idx = tid; idx < 5120; idx += 256) {
        int c = idx & 15, b = (idx >> 4) & 63, u = idx >> 10;
        Bd[(c * 5 + u) * 65 + b] = x[(b * 1024 + 1015 + 2 * u) * 256 + c0 + c];
      }
      __syncthreads();
      for (int c = 0; c < 16; ++c) {
        float bv[5];
#pragma unroll
        for (int u = 0; u < 5; ++u) bv[u] = Bd[(c * 5 + u) * 65 + lane];
        float av[8];
        *(float4*)&av[0] = F4(&Ad[c * 32 + wv * 8]);
        *(float4*)&av[4] = F4(&Ad[c * 32 + wv * 8 + 4]);
#pragma unroll
        for (int i = 0; i < 8; ++i)
#pragma unroll
          for (int t = 0; t < 5; ++t) acc[i][t] += av[i] * bv[t];
      }
    }
#pragma unroll
    for (int i = 0; i < 8; ++i)
#pragma unroll
      for (int t = 0; t < 5; ++t)
        PD[((ks * 512 + oc0 + wv * 8 + i) * 5 + t) * 64 + lane] = acc[i][t];
  }
}

// ===== kB: L1 conv (16 ocp x 8 ks), stage B1=relu(sum4 P0+b1_0); PDs tail ==
__global__ __launch_bounds__(256) void kB(const float* __restrict__ P0,
                                          const float* __restrict__ b1_0,
                                          const float* __restrict__ w2_0,
                                          const float* __restrict__ PD,
                                          float* __restrict__ P1,
                                          float* __restrict__ PDs) {
  __shared__ float smem[12800];  // 1536 W + 11264 B
  const int tid = threadIdx.x, lane = tid & 63, wv = tid >> 6;
  const int ocp = blockIdx.x >> 3, ks = blockIdx.x & 7, oc0 = ocp * 32;
  float* Als = smem;         // [16c][3kk][32oc]
  float* Bls = smem + 1536;  // [(c*11+u)*64+b]
  float acc[8][5];
#pragma unroll
  for (int i = 0; i < 8; ++i)
#pragma unroll
    for (int t = 0; t < 5; ++t) acc[i][t] = 0.f;
  for (int ch = 0; ch < 4; ++ch) {
    const int c0 = ks * 64 + ch * 16;
    if (ch) __syncthreads();
    for (int idx = tid; idx < 1536; idx += 256) {
      int i = idx / 48, r = idx % 48, c = r / 3, kk = r % 3;
      Als[(c * 3 + kk) * 32 + i] = w2_0[(oc0 + i) * 1536 + (c0 + c) * 3 + kk];
    }
    for (int idx = tid; idx < 2816; idx += 256) {  // 16c*11u*16 quads
      int c = idx / 176, r = idx % 176, u = r / 16, b4 = (r & 15) * 4;
      int cc = c0 + c;
      float4 s = {0.f, 0.f, 0.f, 0.f};
#pragma unroll
      for (int p = 0; p < 4; ++p)
        s = add4(s, F4(&P0[((p * 512 + cc) * 11 + u) * 64 + b4]));
      *(float4*)&Bls[(c * 11 + u) * 64 + b4] = relu4(addc4(s, b1_0[cc]));
    }
    __syncthreads();
    for (int c = 0; c < 16; ++c) {
      float bv[11];
#pragma unroll
      for (int u = 0; u < 11; ++u) bv[u] = Bls[(c * 11 + u) * 64 + lane];
      float av[3][8];
#pragma unroll
      for (int kk = 0; kk < 3; ++kk) {
        *(float4*)&av[kk][0] = F4(&Als[(c * 3 + kk) * 32 + wv * 8]);
        *(float4*)&av[kk][4] = F4(&Als[(c * 3 + kk) * 32 + wv * 8 + 4]);
      }
#pragma unroll
      for (int i = 0; i < 8; ++i)
#pragma unroll
        for (int t = 0; t < 5; ++t)
#pragma unroll
          for (int kk = 0; kk < 3; ++kk)
            acc[i][t] += av[kk][i] * bv[2 * t + kk];
    }
  }
#pragma unroll
  for (int i = 0; i < 8; ++i)
#pragma unroll
    for (int t = 0; t < 5; ++t)
      P1[((ks * 512 + oc0 + wv * 8 + i) * 5 + t) * 64 + lane] = acc[i][t];
  // tail: PDs = sum4 PD (one pass, grid-strided over 40960 quads)
  for (int idx = blockIdx.x * 256 + tid; idx < 40960; idx += 128 * 256) {
    int cc = idx / 80, r = idx % 80, u = r / 16, b4 = (r & 15) * 4;
    float4 s = {0.f, 0.f, 0.f, 0.f};
#pragma unroll
    for (int p = 0; p < 4; ++p)
      s = add4(s, F4(&PD[((p * 512 + cc) * 5 + u) * 64 + b4]));
    *(float4*)&PDs[(cc * 5 + u) * 64 + b4] = s;
  }
}

// ===== kC: L2 conv OCT=64 (8 ocp x 8 ks), stage H0 from P1+PDs =============
__global__ __launch_bounds__(256) void kC(const float* __restrict__ P1,
                                          const float* __restrict__ b2_0,
                                          const float* __restrict__ PDs,
                                          const float* __restrict__ bd0,
                                          const float* __restrict__ w1_1,
                                          float* __restrict__ P2,
                                          float* __restrict__ H0f) {
  __shared__ float smem[8192];  // 3072 W + 5120 B
  const int tid = threadIdx.x, lane = tid & 63, wv = tid >> 6;
  const int ocp = blockIdx.x >> 3, ks = blockIdx.x & 7, oc0 = ocp * 64;
  float* Als = smem;         // [16c][3kk][64oc]
  float* Bls = smem + 3072;  // [(c*5+u)*64+b]
  float acc[16][3];
#pragma unroll
  for (int i = 0; i < 16; ++i)
#pragma unroll
    for (int t = 0; t < 3; ++t) acc[i][t] = 0.f;
  for (int ch = 0; ch < 4; ++ch) {
    const int c0 = ks * 64 + ch * 16;
    if (ch) __syncthreads();
    for (int idx = tid; idx < 3072; idx += 256) {
      int i = idx / 48, r = idx % 48, c = r / 3, kk = r % 3;
      Als[(c * 3 + kk) * 64 + i] = w1_1[(oc0 + i) * 1536 + (c0 + c) * 3 + kk];
    }
    for (int idx = tid; idx < 1280; idx += 256) {  // 16c*5u*16 quads
      int c = idx / 80, r = idx % 80, u = r / 16, b4 = (r & 15) * 4;
      int cc = c0 + c;
      float4 s = {0.f, 0.f, 0.f, 0.f};
#pragma unroll
      for (int p = 0; p < 8; ++p)
        s = add4(s, F4(&P1[((p * 512 + cc) * 5 + u) * 64 + b4]));
      s = relu4(addc4(s, b2_0[cc]));
      s = relu4(addc4(add4(s, F4(&PDs[(cc * 5 + u) * 64 + b4])), bd0[cc]));
      *(float4*)&Bls[(c * 5 + u) * 64 + b4] = s;
      if (ocp == 0 && u == 4) *(float4*)&H0f[cc * 64 + b4] = s;
    }
    __syncthreads();
    for (int c = 0; c < 16; ++c) {
      float bv[5];
#pragma unroll
      for (int u = 0; u < 5; ++u) bv[u] = Bls[(c * 5 + u) * 64 + lane];
      float av[3][16];
#pragma unroll
      for (int kk = 0; kk < 3; ++kk)
#pragma unroll
        for (int j = 0; j < 16; j += 4)
          *(float4*)&av[kk][j] = F4(&Als[(c * 3 + kk) * 64 + wv * 16 + j]);
#pragma unroll
      for (int i = 0; i < 16; ++i)
#pragma unroll
        for (int t = 0; t < 3; ++t)
#pragma unroll
          for (int kk = 0; kk < 3; ++kk)
            acc[i][t] += av[kk][i] * bv[t + kk];
    }
  }
#pragma unroll
  for (int i = 0; i < 16; ++i)
#pragma unroll
    for (int t = 0; t < 3; ++t)
      P2[((ks * 512 + oc0 + wv * 16 + i) * 3 + t) * 64 + lane] = acc[i][t];
}

// ===== kD: L3 conv OCT=64 (8 ocp x 8 ks, CCH=64), stage B2 from P2 =========
__global__ __launch_bounds__(256) void kD(const float* __restrict__ P2,
                                          const float* __restrict__ b1_1,
                                          const float* __restrict__ w2_1,
                                          float* __restrict__ P3) {
  __shared__ float smem[24576];  // 12288 W + 12288 B (98.3 KB)
  const int tid = threadIdx.x, lane = tid & 63, wv = tid >> 6;
  const int ocp = blockIdx.x >> 3, ks = blockIdx.x & 7, oc0 = ocp * 64;
  const int c0 = ks * 64;
  float* Als = smem;          // [64c][3kk][64oc]
  float* Bls = smem + 12288;  // [(c*3+u)*64+b]
  float acc[16];
#pragma unroll
  for (int i = 0; i < 16; ++i) acc[i] = 0.f;
  for (int idx = tid; idx < 12288; idx += 256) {
    int i = idx / 192, r = idx % 192, c = r / 3, kk = r % 3;
    Als[(c * 3 + kk) * 64 + i] = w2_1[(oc0 + i) * 1536 + (c0 + c) * 3 + kk];
  }
  for (int idx = tid; idx < 3072; idx += 256) {  // 64c*3u*16 quads
    int c = idx / 48, r = idx % 48, u = r / 16, b4 = (r & 15) * 4;
    int cc = c0 + c;
    float4 s = {0.f, 0.f, 0.f, 0.f};
#pragma unroll
    for (int p = 0; p < 8; ++p)
      s = add4(s, F4(&P2[((p * 512 + cc) * 3 + u) * 64 + b4]));
    *(float4*)&Bls[(c * 3 + u) * 64 + b4] = relu4(addc4(s, b1_1[cc]));
  }
  __syncthreads();
  for (int c = 0; c < 64; ++c) {
    float bv[3];
#pragma unroll
    for (int u = 0; u < 3; ++u) bv[u] = Bls[(c * 3 + u) * 64 + lane];
    float av[3][16];
#pragma unroll
    for (int kk = 0; kk < 3; ++kk)
#pragma unroll
      for (int j = 0; j < 16; j += 4)
        *(float4*)&av[kk][j] = F4(&Als[(c * 3 + kk) * 64 + wv * 16 + j]);
#pragma unroll
    for (int i = 0; i < 16; ++i)
#pragma unroll
      for (int kk = 0; kk < 3; ++kk) acc[i] += av[kk][i] * bv[kk];
  }
#pragma unroll
  for (int i = 0; i < 16; ++i)
    P3[(ks * 512 + oc0 + wv * 16 + i) * 64 + lane] = acc[i];
}

// ===== kE: fc; H1 = relu(relu(sum8 P3 + b2_1) + H0f) inline ================
__global__ __launch_bounds__(256) void kE(const float* __restrict__ P3,
                                          const float* __restrict__ b2_1,
                                          const float* __restrict__ H0f,
                                          const float* __restrict__ fcw,
                                          const float* __restrict__ fcb,
                                          float* __restrict__ out) {
  const int j = blockIdx.x, tid = threadIdx.x;
  const int lane = tid & 63, wv = tid >> 6;
  __shared__ float red[4][64];
  float partial = (wv == 0) ? fcb[j] : 0.f;
  for (int o = wv * 128; o < wv * 128 + 128; ++o) {
    float s = 0.f;
#pragma unroll
    for (int p = 0; p < 8; ++p) s += P3[(p * 512 + o) * 64 + lane];
    float h1 = relu(relu(s + b2_1[o]) + H0f[o * 64 + lane]);
    partial += fcw[j * 512 + o] * h1;
  }
  red[wv][lane] = partial;
  __syncthreads();
  if (wv == 0)
    out[lane * 36 + j] =
        red[0][lane] + red[1][lane] + red[2][lane] + red[3][lane];
}

extern "C" void kernel_launch(void* const* d_in, const int* in_sizes, int n_in,
                              void* d_out, int out_size, void* d_ws, size_t ws_size,
                              hipStream_t stream) {
  const float* x    = (const float*)d_in[0];
  const float* w1_0 = (const float*)d_in[4];
  const float* b1_0 = (const float*)d_in[5];
  const float* w2_0 = (const float*)d_in[6];
  const float* b2_0 = (const float*)d_in[7];
  const float* wd0  = (const float*)d_in[8];
  const float* bd0  = (const float*)d_in[9];
  const float* w1_1 = (const float*)d_in[10];
  const float* b1_1 = (const float*)d_in[11];
  const float* w2_1 = (const float*)d_in[12];
  const float* b2_1 = (const float*)d_in[13];
  const float* fcw  = (const float*)d_in[14];
  const float* fcb  = (const float*)d_in[15];
  float* out = (float*)d_out;

  float* P0  = (float*)d_ws;       // 4*512*11*64  = 1,441,792
  float* PD  = P0 + 1441792;       // 4*512*5*64   =   655,360
  float* PDs = PD + 655360;        // 512*5*64     =   163,840
  float* P1  = PDs + 163840;       // 8*512*5*64   = 1,310,720
  float* P2  = P1 + 1310720;       // 8*512*3*64   =   786,432
  float* P3  = P2 + 786432;        // 8*512*64     =   262,144
  float* H0f = P3 + 262144;        // 512*64       =    32,768

  kA<<<192, 256, 0, stream>>>(x, w1_0, wd0, P0, PD);
  kB<<<128, 256, 0, stream>>>(P0, b1_0, w2_0, PD, P1, PDs);
  kC<<<64, 256, 0, stream>>>(P1, b2_0, PDs, bd0, w1_1, P2, H0f);
  kD<<<64, 256, 0, stream>>>(P2, b1_1, w2_1, P3);
  kE<<<36, 256, 0, stream>>>(P3, b2_1, H0f, fcw, fcb, out);
}

// Round 14
// 151.145 us; speedup vs baseline: 1.1869x; 1.1869x over previous
//
#include <hip/hip_runtime.h>

// TCN, last-timestep receptive-field cone. 7 launches, all bodies from
// previously-verified rounds (9, 12, 13) with constant-level edits only:
//   1 k_l0dn (r9): L0 conv x->P0[8ks], down conv x->PD[8ks]
//   2 red0   (r9): B1[512][64][12] = relu(sum8 P0 + b1_0)
//   3 convL1 (r9): B1 -> P1[16ks]
//   4 red1   (r9): H0[512][64][12] = relu(relu(sum16 P1+b2_0)+sum8 PD+bd0)
//   5 convL2 (r9, NCH 2->4): H0 -> P2[8ks]
//   6 kD     (r12, p 16->8): stage B2=relu(sum8 P2+b1_1); L3 conv -> P3[8ks]
//   7 kE     (r13, residual via H0[oc][b][12] u=4): fc with fused sum8 P3
// Activations [c][b][TP]; partials [ks][512][T][64].
// t maps: L0 u=ti+kk (x t=1011+u); down u=tj (x t=1015+2u);
// L1 u=2tj+kk (B1); L2 u=tk+kk (H0); L3 u=kk (B2); residual H0 u=4 (t=1023).

#define OUTD 36
#define F4(q) (*(const float4*)(q))

__device__ __forceinline__ float relu(float v) { return fmaxf(v, 0.f); }
__device__ __forceinline__ float4 relu4(float4 v) {
  v.x = fmaxf(v.x, 0.f); v.y = fmaxf(v.y, 0.f);
  v.z = fmaxf(v.z, 0.f); v.w = fmaxf(v.w, 0.f);
  return v;
}
__device__ __forceinline__ float4 add4(float4 a, float4 b) {
  a.x += b.x; a.y += b.y; a.z += b.z; a.w += b.w;
  return a;
}
__device__ __forceinline__ float4 addc4(float4 a, float c) {
  a.x += c; a.y += c; a.z += c; a.w += c;
  return a;
}

// ---- generic split-K conv-GEMM body (round-9 verbatim) ------------------
template <int CIN, int TS_N, int TP, int TOUT, int S, int D, int OFF, int TAPS,
          int OCT, int CCH, int NCH, bool SRC_X, int TS_BASE, int TS_STEP>
__device__ __forceinline__ void conv_body(int bx, int by,
                                          const float* __restrict__ src,
                                          const float* __restrict__ w,
                                          float* __restrict__ Pout) {
    const int tid = threadIdx.x, lane = tid & 63, wv = tid >> 6;
    const int oc0 = bx * OCT;
    constexpr int OCR = OCT / 4;
    __shared__ float Als[CCH * TAPS * OCT];
    __shared__ float Bls[CCH * 64 * TP];
    float acc[OCR][TOUT];
#pragma unroll
    for (int i = 0; i < OCR; ++i)
#pragma unroll
        for (int t = 0; t < TOUT; ++t) acc[i][t] = 0.f;

    for (int ch = 0; ch < NCH; ++ch) {
        const int c0 = (by * NCH + ch) * CCH;
        if (ch) __syncthreads();
        for (int idx = tid; idx < OCT * CCH * TAPS; idx += 256) {
            int i = idx / (CCH * TAPS), r = idx % (CCH * TAPS);
            int c = r / TAPS, kk = r % TAPS;
            Als[(c * TAPS + kk) * OCT + i] =
                w[(size_t)(oc0 + i) * (CIN * TAPS) + (c0 + c) * TAPS + kk];
        }
        if constexpr (SRC_X) {
            for (int idx = tid; idx < CCH * TS_N * 64; idx += 256) {
                int c = idx % CCH, rb = idx / CCH;
                int b = rb & 63, u = rb >> 6;
                Bls[(c * 64 + b) * TP + u] =
                    src[((size_t)b * 1024 + 1011 + TS_BASE + TS_STEP * u) * 256 +
                        c0 + c];
            }
        } else {
            const float4* gp = (const float4*)(src + (size_t)c0 * 64 * TP);
            float4* lp = (float4*)Bls;
            for (int idx = tid; idx < CCH * 64 * TP / 4; idx += 256)
                lp[idx] = gp[idx];
        }
        __syncthreads();
        constexpr int NLOAD = (TP % 4 == 0) ? TP : TS_N;
        for (int c = 0; c < CCH; ++c) {
            float bv[NLOAD];
            if constexpr (TP % 4 == 0) {
#pragma unroll
                for (int q = 0; q < TP / 4; ++q)
                    *(float4*)&bv[4 * q] =
                        *(const float4*)&Bls[(c * 64 + lane) * TP + 4 * q];
            } else {
#pragma unroll
                for (int u = 0; u < TS_N; ++u)
                    bv[u] = Bls[(c * 64 + lane) * TP + u];
            }
            float av[TAPS][OCR];
#pragma unroll
            for (int kk = 0; kk < TAPS; ++kk)
#pragma unroll
                for (int j = 0; j < OCR; j += 4)
                    *(float4*)&av[kk][j] =
                        *(const float4*)&Als[(c * TAPS + kk) * OCT + wv * OCR + j];
#pragma unroll
            for (int i = 0; i < OCR; ++i)
#pragma unroll
                for (int t = 0; t < TOUT; ++t)
#pragma unroll
                    for (int kk = 0; kk < TAPS; ++kk)
                        acc[i][t] += av[kk][i] * bv[S * t + D * kk + OFF];
        }
    }
#pragma unroll
    for (int i = 0; i < OCR; ++i)
#pragma unroll
        for (int t = 0; t < TOUT; ++t)
            Pout[(((size_t)by * 512 + oc0 + wv * OCR + i) * TOUT + t) * 64 +
                 lane] = acc[i][t];
}

template <int CIN, int TS_N, int TP, int TOUT, int S, int D, int OFF, int TAPS,
          int OCT, int CCH, int NCH, bool SRC_X, int TS_BASE, int TS_STEP>
__global__ __launch_bounds__(256) void k_conv(const float* __restrict__ src,
                                              const float* __restrict__ w,
                                              float* __restrict__ Pout) {
    conv_body<CIN, TS_N, TP, TOUT, S, D, OFF, TAPS, OCT, CCH, NCH, SRC_X,
              TS_BASE, TS_STEP>(blockIdx.x, blockIdx.y, src, w, Pout);
}

// merged L0 (blocks 0..255: 32 ocp x 8 ks) + down (256..383: 16 x 8) [r9]
__global__ __launch_bounds__(256) void k_l0dn(const float* __restrict__ x,
                                              const float* __restrict__ w1_0,
                                              const float* __restrict__ wd0,
                                              float* __restrict__ P0,
                                              float* __restrict__ PD) {
    if (blockIdx.x < 256) {
        conv_body<256, 13, 13, 11, 1, 1, 0, 3, 16, 16, 2, true, 0, 1>(
            blockIdx.x >> 3, blockIdx.x & 7, x, w1_0, P0);
    } else {
        const int q = blockIdx.x - 256;
        conv_body<256, 5, 5, 5, 1, 0, 0, 1, 32, 16, 2, true, 4, 2>(
            q >> 3, q & 7, x, wd0, PD);
    }
}

// ---- reduce (round-9 verbatim): out[oc][b][TPo] -------------------------
template <int KS1, int T, int TPo, int KS2, bool RES>
__global__ __launch_bounds__(256) void k_red(const float* __restrict__ P1,
                                             const float* __restrict__ bias1,
                                             const float* __restrict__ P2,
                                             const float* __restrict__ bias2,
                                             const float* __restrict__ res,
                                             float* __restrict__ outp) {
    const int oc = blockIdx.x, tid = threadIdx.x;
    __shared__ float Sm[64 * TPo];
    if constexpr (TPo > 1) {
        for (int i = tid; i < 64 * TPo; i += 256) Sm[i] = 0.f;
        __syncthreads();
    }
    if (tid < T * 16) {
        const int t = tid / 16, b4 = (tid % 16) * 4;
        float4 s = make_float4(0.f, 0.f, 0.f, 0.f);
#pragma unroll
        for (int p = 0; p < KS1; ++p)
            s = add4(s, F4(P1 + (((size_t)p * 512 + oc) * T + t) * 64 + b4));
        const float b1 = bias1[oc];
        s = relu4(addc4(s, b1));
        if constexpr (KS2 > 0) {
            float4 s2 = make_float4(0.f, 0.f, 0.f, 0.f);
#pragma unroll
            for (int p = 0; p < KS2; ++p)
                s2 = add4(s2, F4(P2 + (((size_t)p * 512 + oc) * T + t) * 64 + b4));
            s = relu4(addc4(add4(s, s2), bias2[oc]));
        }
        if constexpr (RES) {
            s.x = fmaxf(s.x + res[((size_t)oc * 64 + b4 + 0) * 12 + 4], 0.f);
            s.y = fmaxf(s.y + res[((size_t)oc * 64 + b4 + 1) * 12 + 4], 0.f);
            s.z = fmaxf(s.z + res[((size_t)oc * 64 + b4 + 2) * 12 + 4], 0.f);
            s.w = fmaxf(s.w + res[((size_t)oc * 64 + b4 + 3) * 12 + 4], 0.f);
        }
        if constexpr (TPo == 1) {
            *(float4*)(outp + (size_t)oc * 64 + b4) = s;
        } else {
            Sm[(b4 + 0) * TPo + t] = s.x;
            Sm[(b4 + 1) * TPo + t] = s.y;
            Sm[(b4 + 2) * TPo + t] = s.z;
            Sm[(b4 + 3) * TPo + t] = s.w;
        }
    }
    if constexpr (TPo > 1) {
        __syncthreads();
        float4* op = (float4*)(outp + (size_t)oc * 64 * TPo);
        for (int i = tid; i < 64 * TPo / 4; i += 256)
            op[i] = *(const float4*)&Sm[4 * i];
    }
}

// ===== kD (round-12 verbatim, p<16 -> p<8): L3 conv with fused B2 staging ==
__global__ __launch_bounds__(256) void kD(const float* __restrict__ P2,
                                          const float* __restrict__ b1_1,
                                          const float* __restrict__ w2_1,
                                          float* __restrict__ P3) {
  __shared__ float smem[18432];  // 6144 W + 12288 B
  const int tid = threadIdx.x, lane = tid & 63, wv = tid >> 6;
  const int ocp = blockIdx.x >> 3, ks = blockIdx.x & 7, oc0 = ocp * 32;
  const int c0 = ks * 64;
  float* Als = smem;         // [64c][3kk][32oc]
  float* Bls = smem + 6144;  // [(c*3+u)*64+b]
  float acc[8];
#pragma unroll
  for (int i = 0; i < 8; ++i) acc[i] = 0.f;
  for (int idx = tid; idx < 6144; idx += 256) {
    int i = idx / 192, r = idx % 192, c = r / 3, kk = r % 3;
    Als[(c * 3 + kk) * 32 + i] = w2_1[(oc0 + i) * 1536 + (c0 + c) * 3 + kk];
  }
  for (int idx = tid; idx < 3072; idx += 256) {  // 64c*3u*16 quads
    int c = idx / 48, r = idx % 48, u = r / 16, b4 = (r & 15) * 4;
    int cc = c0 + c;
    float4 s = {0.f, 0.f, 0.f, 0.f};
#pragma unroll
    for (int p = 0; p < 8; ++p)
      s = add4(s, F4(&P2[((p * 512 + cc) * 3 + u) * 64 + b4]));
    *(float4*)&Bls[(c * 3 + u) * 64 + b4] = relu4(addc4(s, b1_1[cc]));
  }
  __syncthreads();
  for (int c = 0; c < 64; ++c) {
    float bv[3];
#pragma unroll
    for (int u = 0; u < 3; ++u) bv[u] = Bls[(c * 3 + u) * 64 + lane];
    float av[3][8];
#pragma unroll
    for (int kk = 0; kk < 3; ++kk) {
      *(float4*)&av[kk][0] = F4(&Als[(c * 3 + kk) * 32 + wv * 8]);
      *(float4*)&av[kk][4] = F4(&Als[(c * 3 + kk) * 32 + wv * 8 + 4]);
    }
#pragma unroll
    for (int i = 0; i < 8; ++i)
#pragma unroll
      for (int kk = 0; kk < 3; ++kk) acc[i] += av[kk][i] * bv[kk];
  }
#pragma unroll
  for (int i = 0; i < 8; ++i)
    P3[(ks * 512 + oc0 + wv * 8 + i) * 64 + lane] = acc[i];
}

// ===== kE (round-13 verbatim; residual from H0 [oc][b][12] at u=4) =========
__global__ __launch_bounds__(256) void kE(const float* __restrict__ P3,
                                          const float* __restrict__ b2_1,
                                          const float* __restrict__ H0,
                                          const float* __restrict__ fcw,
                                          const float* __restrict__ fcb,
                                          float* __restrict__ out) {
  const int j = blockIdx.x, tid = threadIdx.x;
  const int lane = tid & 63, wv = tid >> 6;
  __shared__ float red[4][64];
  float partial = (wv == 0) ? fcb[j] : 0.f;
  for (int o = wv * 128; o < wv * 128 + 128; ++o) {
    float s = 0.f;
#pragma unroll
    for (int p = 0; p < 8; ++p) s += P3[(p * 512 + o) * 64 + lane];
    float h1 = relu(relu(s + b2_1[o]) + H0[((size_t)o * 64 + lane) * 12 + 4]);
    partial += fcw[j * 512 + o] * h1;
  }
  red[wv][lane] = partial;
  __syncthreads();
  if (wv == 0)
    out[lane * OUTD + j] =
        red[0][lane] + red[1][lane] + red[2][lane] + red[3][lane];
}

extern "C" void kernel_launch(void* const* d_in, const int* in_sizes, int n_in,
                              void* d_out, int out_size, void* d_ws, size_t ws_size,
                              hipStream_t stream) {
    const float* x    = (const float*)d_in[0];
    const float* w1_0 = (const float*)d_in[4];
    const float* b1_0 = (const float*)d_in[5];
    const float* w2_0 = (const float*)d_in[6];
    const float* b2_0 = (const float*)d_in[7];
    const float* wd0  = (const float*)d_in[8];
    const float* bd0  = (const float*)d_in[9];
    const float* w1_1 = (const float*)d_in[10];
    const float* b1_1 = (const float*)d_in[11];
    const float* w2_1 = (const float*)d_in[12];
    const float* b2_1 = (const float*)d_in[13];
    const float* fcw  = (const float*)d_in[14];
    const float* fcb  = (const float*)d_in[15];
    float* out = (float*)d_out;

    float* P0  = (float*)d_ws;                 // 8*512*11*64 = 2,883,584
    float* B1  = P0 + 8 * 512 * 11 * 64;       // 512*64*12   =   393,216
    float* P1  = B1 + 512 * 64 * 12;           // 16*512*5*64 = 2,621,440
    float* PD  = P1 + 16 * 512 * 5 * 64;       // 8*512*5*64  = 1,310,720
    float* H0  = PD + 8 * 512 * 5 * 64;        // 512*64*12   =   393,216
    float* P2  = H0 + 512 * 64 * 12;           // 8*512*3*64  =   786,432
    float* P3  = P2 + 8 * 512 * 3 * 64;        // 8*512*64    =   262,144

    // 1. L0 + down (round-9 verbatim)
    k_l0dn<<<384, 256, 0, stream>>>(x, w1_0, wd0, P0, PD);
    // 2. red0: B1 = relu(sum8 P0 + b1_0)
    k_red<8, 11, 12, 0, false><<<512, 256, 0, stream>>>(P0, b1_0, nullptr,
                                                        nullptr, nullptr, B1);
    // 3. convL1: B1 -> P1 (16 ks)
    k_conv<512, 11, 12, 5, 2, 1, 0, 3, 32, 16, 2, false, 0, 0>
        <<<dim3(16, 16), 256, 0, stream>>>(B1, w2_0, P1);
    // 4. red1: H0 = relu(relu(sum16 P1 + b2_0) + sum8 PD + bd0)
    k_red<16, 5, 12, 8, false><<<512, 256, 0, stream>>>(P1, b2_0, PD, bd0,
                                                        nullptr, H0);
    // 5. convL2: H0 -> P2 (8 ks; NCH=4)
    k_conv<512, 5, 12, 3, 1, 1, 0, 3, 32, 16, 4, false, 0, 0>
        <<<dim3(16, 8), 256, 0, stream>>>(H0, w1_1, P2);
    // 6. kD: fused B2 staging + L3 conv -> P3 (8 ks)
    kD<<<128, 256, 0, stream>>>(P2, b1_1, w2_1, P3);
    // 7. kE: fc with fused sum8 P3 + residual
    kE<<<OUTD, 256, 0, stream>>>(P3, b2_1, H0, fcw, fcb, out);
}

// Round 15
// 121.802 us; speedup vs baseline: 1.4729x; 1.2409x over previous
//
#include <hip/hip_runtime.h>

// TCN, last-timestep receptive-field cone. 7 launches:
//   1 k_l0dn (r9):  L0 conv x->P0[8ks], down conv x->PD[8ks]
//   2 red0   (r9):  B1[512][64][12] = relu(sum8 P0 + b1_0)
//   3 convL1 (r9):  B1 -> P1[16ks]
//   4 red1   (new): H0[512][64][12] = relu(relu(sum16 P1+b2_0)+sum8 PD+bd0)
//                   + emits H0f[512][64] = H0 at u=4 (t=1023), coalesced
//   5 convL2 (r14): H0 -> P2[8ks]
//   6 kD     (r14): stage B2=relu(sum8 P2+b1_1); L3 conv -> P3[8ks]
//   7 kE     (new): 2-phase fc — H1 staged in LDS (coalesced reads), then dot
// Activations [c][b][TP]; partials [ks][512][T][64].
// t maps: L0 u=ti+kk (x t=1011+u); down u=tj (x t=1015+2u);
// L1 u=2tj+kk (B1); L2 u=tk+kk (H0); L3 u=kk (B2); residual H0 u=4 (t=1023).

#define OUTD 36
#define F4(q) (*(const float4*)(q))

__device__ __forceinline__ float4 relu4(float4 v) {
  v.x = fmaxf(v.x, 0.f); v.y = fmaxf(v.y, 0.f);
  v.z = fmaxf(v.z, 0.f); v.w = fmaxf(v.w, 0.f);
  return v;
}
__device__ __forceinline__ float4 add4(float4 a, float4 b) {
  a.x += b.x; a.y += b.y; a.z += b.z; a.w += b.w;
  return a;
}
__device__ __forceinline__ float4 addc4(float4 a, float c) {
  a.x += c; a.y += c; a.z += c; a.w += c;
  return a;
}

// ---- generic split-K conv-GEMM body (round-9 verbatim) ------------------
template <int CIN, int TS_N, int TP, int TOUT, int S, int D, int OFF, int TAPS,
          int OCT, int CCH, int NCH, bool SRC_X, int TS_BASE, int TS_STEP>
__device__ __forceinline__ void conv_body(int bx, int by,
                                          const float* __restrict__ src,
                                          const float* __restrict__ w,
                                          float* __restrict__ Pout) {
    const int tid = threadIdx.x, lane = tid & 63, wv = tid >> 6;
    const int oc0 = bx * OCT;
    constexpr int OCR = OCT / 4;
    __shared__ float Als[CCH * TAPS * OCT];
    __shared__ float Bls[CCH * 64 * TP];
    float acc[OCR][TOUT];
#pragma unroll
    for (int i = 0; i < OCR; ++i)
#pragma unroll
        for (int t = 0; t < TOUT; ++t) acc[i][t] = 0.f;

    for (int ch = 0; ch < NCH; ++ch) {
        const int c0 = (by * NCH + ch) * CCH;
        if (ch) __syncthreads();
        for (int idx = tid; idx < OCT * CCH * TAPS; idx += 256) {
            int i = idx / (CCH * TAPS), r = idx % (CCH * TAPS);
            int c = r / TAPS, kk = r % TAPS;
            Als[(c * TAPS + kk) * OCT + i] =
                w[(size_t)(oc0 + i) * (CIN * TAPS) + (c0 + c) * TAPS + kk];
        }
        if constexpr (SRC_X) {
            for (int idx = tid; idx < CCH * TS_N * 64; idx += 256) {
                int c = idx % CCH, rb = idx / CCH;
                int b = rb & 63, u = rb >> 6;
                Bls[(c * 64 + b) * TP + u] =
                    src[((size_t)b * 1024 + 1011 + TS_BASE + TS_STEP * u) * 256 +
                        c0 + c];
            }
        } else {
            const float4* gp = (const float4*)(src + (size_t)c0 * 64 * TP);
            float4* lp = (float4*)Bls;
            for (int idx = tid; idx < CCH * 64 * TP / 4; idx += 256)
                lp[idx] = gp[idx];
        }
        __syncthreads();
        constexpr int NLOAD = (TP % 4 == 0) ? TP : TS_N;
        for (int c = 0; c < CCH; ++c) {
            float bv[NLOAD];
            if constexpr (TP % 4 == 0) {
#pragma unroll
                for (int q = 0; q < TP / 4; ++q)
                    *(float4*)&bv[4 * q] =
                        *(const float4*)&Bls[(c * 64 + lane) * TP + 4 * q];
            } else {
#pragma unroll
                for (int u = 0; u < TS_N; ++u)
                    bv[u] = Bls[(c * 64 + lane) * TP + u];
            }
            float av[TAPS][OCR];
#pragma unroll
            for (int kk = 0; kk < TAPS; ++kk)
#pragma unroll
                for (int j = 0; j < OCR; j += 4)
                    *(float4*)&av[kk][j] =
                        *(const float4*)&Als[(c * TAPS + kk) * OCT + wv * OCR + j];
#pragma unroll
            for (int i = 0; i < OCR; ++i)
#pragma unroll
                for (int t = 0; t < TOUT; ++t)
#pragma unroll
                    for (int kk = 0; kk < TAPS; ++kk)
                        acc[i][t] += av[kk][i] * bv[S * t + D * kk + OFF];
        }
    }
#pragma unroll
    for (int i = 0; i < OCR; ++i)
#pragma unroll
        for (int t = 0; t < TOUT; ++t)
            Pout[(((size_t)by * 512 + oc0 + wv * OCR + i) * TOUT + t) * 64 +
                 lane] = acc[i][t];
}

template <int CIN, int TS_N, int TP, int TOUT, int S, int D, int OFF, int TAPS,
          int OCT, int CCH, int NCH, bool SRC_X, int TS_BASE, int TS_STEP>
__global__ __launch_bounds__(256) void k_conv(const float* __restrict__ src,
                                              const float* __restrict__ w,
                                              float* __restrict__ Pout) {
    conv_body<CIN, TS_N, TP, TOUT, S, D, OFF, TAPS, OCT, CCH, NCH, SRC_X,
              TS_BASE, TS_STEP>(blockIdx.x, blockIdx.y, src, w, Pout);
}

// merged L0 (blocks 0..255: 32 ocp x 8 ks) + down (256..383: 16 x 8) [r9]
__global__ __launch_bounds__(256) void k_l0dn(const float* __restrict__ x,
                                              const float* __restrict__ w1_0,
                                              const float* __restrict__ wd0,
                                              float* __restrict__ P0,
                                              float* __restrict__ PD) {
    if (blockIdx.x < 256) {
        conv_body<256, 13, 13, 11, 1, 1, 0, 3, 16, 16, 2, true, 0, 1>(
            blockIdx.x >> 3, blockIdx.x & 7, x, w1_0, P0);
    } else {
        const int q = blockIdx.x - 256;
        conv_body<256, 5, 5, 5, 1, 0, 0, 1, 32, 16, 2, true, 4, 2>(
            q >> 3, q & 7, x, wd0, PD);
    }
}

// ---- red0 (round-9 k_red<8,11,12,0,false> verbatim): B1[oc][b][12] ------
__global__ __launch_bounds__(256) void k_red0(const float* __restrict__ P0,
                                              const float* __restrict__ b1_0,
                                              float* __restrict__ B1) {
    const int oc = blockIdx.x, tid = threadIdx.x;
    __shared__ float Sm[64 * 12];
    for (int i = tid; i < 768; i += 256) Sm[i] = 0.f;
    __syncthreads();
    if (tid < 176) {
        const int t = tid / 16, b4 = (tid % 16) * 4;
        float4 s = make_float4(0.f, 0.f, 0.f, 0.f);
#pragma unroll
        for (int p = 0; p < 8; ++p)
            s = add4(s, F4(P0 + (((size_t)p * 512 + oc) * 11 + t) * 64 + b4));
        s = relu4(addc4(s, b1_0[oc]));
        Sm[(b4 + 0) * 12 + t] = s.x;
        Sm[(b4 + 1) * 12 + t] = s.y;
        Sm[(b4 + 2) * 12 + t] = s.z;
        Sm[(b4 + 3) * 12 + t] = s.w;
    }
    __syncthreads();
    float4* op = (float4*)(B1 + (size_t)oc * 768);
    for (int i = tid; i < 192; i += 256) op[i] = *(const float4*)&Sm[4 * i];
}

// ---- red1 (r9 k_red<16,5,12,8> + coalesced H0f emit): H0[oc][b][12] -----
__global__ __launch_bounds__(256) void k_red1(const float* __restrict__ P1,
                                              const float* __restrict__ b2_0,
                                              const float* __restrict__ PD,
                                              const float* __restrict__ bd0,
                                              float* __restrict__ H0,
                                              float* __restrict__ H0f) {
    const int oc = blockIdx.x, tid = threadIdx.x;
    __shared__ float Sm[64 * 12];
    for (int i = tid; i < 768; i += 256) Sm[i] = 0.f;
    __syncthreads();
    if (tid < 80) {
        const int t = tid / 16, b4 = (tid % 16) * 4;
        float4 s = make_float4(0.f, 0.f, 0.f, 0.f);
#pragma unroll
        for (int p = 0; p < 16; ++p)
            s = add4(s, F4(P1 + (((size_t)p * 512 + oc) * 5 + t) * 64 + b4));
        s = relu4(addc4(s, b2_0[oc]));
        float4 s2 = make_float4(0.f, 0.f, 0.f, 0.f);
#pragma unroll
        for (int p = 0; p < 8; ++p)
            s2 = add4(s2, F4(PD + (((size_t)p * 512 + oc) * 5 + t) * 64 + b4));
        s = relu4(addc4(add4(s, s2), bd0[oc]));
        Sm[(b4 + 0) * 12 + t] = s.x;
        Sm[(b4 + 1) * 12 + t] = s.y;
        Sm[(b4 + 2) * 12 + t] = s.z;
        Sm[(b4 + 3) * 12 + t] = s.w;
        if (t == 4) *(float4*)&H0f[(size_t)oc * 64 + b4] = s;
    }
    __syncthreads();
    float4* op = (float4*)(H0 + (size_t)oc * 768);
    for (int i = tid; i < 192; i += 256) op[i] = *(const float4*)&Sm[4 * i];
}

// ===== kD (r14 verbatim): L3 conv with fused B2 staging (sum8 P2) ==========
__global__ __launch_bounds__(256) void kD(const float* __restrict__ P2,
                                          const float* __restrict__ b1_1,
                                          const float* __restrict__ w2_1,
                                          float* __restrict__ P3) {
  __shared__ float smem[18432];  // 6144 W + 12288 B
  const int tid = threadIdx.x, lane = tid & 63, wv = tid >> 6;
  const int ocp = blockIdx.x >> 3, ks = blockIdx.x & 7, oc0 = ocp * 32;
  const int c0 = ks * 64;
  float* Als = smem;         // [64c][3kk][32oc]
  float* Bls = smem + 6144;  // [(c*3+u)*64+b]
  float acc[8];
#pragma unroll
  for (int i = 0; i < 8; ++i) acc[i] = 0.f;
  for (int idx = tid; idx < 6144; idx += 256) {
    int i = idx / 192, r = idx % 192, c = r / 3, kk = r % 3;
    Als[(c * 3 + kk) * 32 + i] = w2_1[(oc0 + i) * 1536 + (c0 + c) * 3 + kk];
  }
  for (int idx = tid; idx < 3072; idx += 256) {  // 64c*3u*16 quads
    int c = idx / 48, r = idx % 48, u = r / 16, b4 = (r & 15) * 4;
    int cc = c0 + c;
    float4 s = {0.f, 0.f, 0.f, 0.f};
#pragma unroll
    for (int p = 0; p < 8; ++p)
      s = add4(s, F4(&P2[((p * 512 + cc) * 3 + u) * 64 + b4]));
    *(float4*)&Bls[(c * 3 + u) * 64 + b4] = relu4(addc4(s, b1_1[cc]));
  }
  __syncthreads();
  for (int c = 0; c < 64; ++c) {
    float bv[3];
#pragma unroll
    for (int u = 0; u < 3; ++u) bv[u] = Bls[(c * 3 + u) * 64 + lane];
    float av[3][8];
#pragma unroll
    for (int kk = 0; kk < 3; ++kk) {
      *(float4*)&av[kk][0] = F4(&Als[(c * 3 + kk) * 32 + wv * 8]);
      *(float4*)&av[kk][4] = F4(&Als[(c * 3 + kk) * 32 + wv * 8 + 4]);
    }
#pragma unroll
    for (int i = 0; i < 8; ++i)
#pragma unroll
      for (int kk = 0; kk < 3; ++kk) acc[i] += av[kk][i] * bv[kk];
  }
#pragma unroll
  for (int i = 0; i < 8; ++i)
    P3[(ks * 512 + oc0 + wv * 8 + i) * 64 + lane] = acc[i];
}

// ===== kE (new): 2-phase fc — H1 half staged in LDS, then wave dot =========
__global__ __launch_bounds__(256) void kE(const float* __restrict__ P3,
                                          const float* __restrict__ b2_1,
                                          const float* __restrict__ H0f,
                                          const float* __restrict__ fcw,
                                          const float* __restrict__ fcb,
                                          float* __restrict__ out) {
  const int j = blockIdx.x, tid = threadIdx.x;
  const int lane = tid & 63, wv = tid >> 6;
  __shared__ float H1s[16384];  // [256 oc_l][64 b] per half (64 KB)
  __shared__ float red[4][64];
  float partial = (wv == 0) ? fcb[j] : 0.f;
  for (int half = 0; half < 2; ++half) {
    const int ocbase = half * 256;
    if (half) __syncthreads();  // previous half's LDS reads complete
    // phase 1: H1s = relu(relu(sum8 P3 + b2_1) + H0f), coalesced quads
    for (int idx = tid; idx < 4096; idx += 256) {  // 256 oc * 16 quads
      int oc_l = idx >> 4, b4 = (idx & 15) * 4;
      int oc = ocbase + oc_l;
      float4 s = {0.f, 0.f, 0.f, 0.f};
#pragma unroll
      for (int p = 0; p < 8; ++p)
        s = add4(s, F4(&P3[(p * 512 + oc) * 64 + b4]));
      s = relu4(addc4(s, b2_1[oc]));
      s = relu4(add4(s, F4(&H0f[(size_t)oc * 64 + b4])));
      *(float4*)&H1s[oc_l * 64 + b4] = s;
    }
    __syncthreads();
    // phase 2: each wave accumulates its 64-oc slice (lane = batch)
#pragma unroll 8
    for (int r = 0; r < 64; ++r) {
      int oc_l = wv * 64 + r;
      partial += fcw[j * 512 + ocbase + oc_l] * H1s[oc_l * 64 + lane];
    }
  }
  red[wv][lane] = partial;
  __syncthreads();
  if (wv == 0)
    out[lane * OUTD + j] =
        red[0][lane] + red[1][lane] + red[2][lane] + red[3][lane];
}

extern "C" void kernel_launch(void* const* d_in, const int* in_sizes, int n_in,
                              void* d_out, int out_size, void* d_ws, size_t ws_size,
                              hipStream_t stream) {
    const float* x    = (const float*)d_in[0];
    const float* w1_0 = (const float*)d_in[4];
    const float* b1_0 = (const float*)d_in[5];
    const float* w2_0 = (const float*)d_in[6];
    const float* b2_0 = (const float*)d_in[7];
    const float* wd0  = (const float*)d_in[8];
    const float* bd0  = (const float*)d_in[9];
    const float* w1_1 = (const float*)d_in[10];
    const float* b1_1 = (const float*)d_in[11];
    const float* w2_1 = (const float*)d_in[12];
    const float* b2_1 = (const float*)d_in[13];
    const float* fcw  = (const float*)d_in[14];
    const float* fcb  = (const float*)d_in[15];
    float* out = (float*)d_out;

    float* P0  = (float*)d_ws;                 // 8*512*11*64 = 2,883,584
    float* B1  = P0 + 8 * 512 * 11 * 64;       // 512*64*12   =   393,216
    float* P1  = B1 + 512 * 64 * 12;           // 16*512*5*64 = 2,621,440
    float* PD  = P1 + 16 * 512 * 5 * 64;       // 8*512*5*64  = 1,310,720
    float* H0  = PD + 8 * 512 * 5 * 64;        // 512*64*12   =   393,216
    float* P2  = H0 + 512 * 64 * 12;           // 8*512*3*64  =   786,432
    float* P3  = P2 + 8 * 512 * 3 * 64;        // 8*512*64    =   262,144
    float* H0f = P3 + 8 * 512 * 64;            // 512*64      =    32,768

    // 1. L0 + down
    k_l0dn<<<384, 256, 0, stream>>>(x, w1_0, wd0, P0, PD);
    // 2. red0: B1 = relu(sum8 P0 + b1_0)
    k_red0<<<512, 256, 0, stream>>>(P0, b1_0, B1);
    // 3. convL1: B1 -> P1 (16 ks)
    k_conv<512, 11, 12, 5, 2, 1, 0, 3, 32, 16, 2, false, 0, 0>
        <<<dim3(16, 16), 256, 0, stream>>>(B1, w2_0, P1);
    // 4. red1: H0 (+H0f) = relu(relu(sum16 P1 + b2_0) + sum8 PD + bd0)
    k_red1<<<512, 256, 0, stream>>>(P1, b2_0, PD, bd0, H0, H0f);
    // 5. convL2: H0 -> P2 (8 ks; NCH=4)
    k_conv<512, 5, 12, 3, 1, 1, 0, 3, 32, 16, 4, false, 0, 0>
        <<<dim3(16, 8), 256, 0, stream>>>(H0, w1_1, P2);
    // 6. kD: fused B2 staging + L3 conv -> P3 (8 ks)
    kD<<<128, 256, 0, stream>>>(P2, b1_1, w2_1, P3);
    // 7. kE: 2-phase fc with fused sum8 P3 + coalesced residual
    kE<<<OUTD, 256, 0, stream>>>(P3, b2_1, H0f, fcw, fcb, out);
}